// Round 10
// baseline (296.204 us; speedup 1.0000x reference)
//
#include <hip/hip_runtime.h>
#include <stdint.h>

typedef unsigned int u32;
typedef __attribute__((ext_vector_type(8))) __bf16 bf16x8;
typedef __attribute__((ext_vector_type(8))) short s16x8;
typedef __attribute__((ext_vector_type(4))) short s16x4;
typedef __attribute__((ext_vector_type(4))) float f32x4;

// ---------- helpers ----------

__device__ __forceinline__ short f2bf(float f) {
    __bf16 h = (__bf16)f;               // native v_cvt, RNE
    return __builtin_bit_cast(short, h);
}

__device__ __forceinline__ bf16x8 asbf(s16x8 v) {
    return __builtin_bit_cast(bf16x8, v);
}

__device__ __forceinline__ f32x4 mfma32(s16x8 a, s16x8 b, f32x4 c) {
    return __builtin_amdgcn_mfma_f32_16x16x32_bf16(asbf(a), asbf(b), c, 0, 0, 0);
}

// async global->LDS, 16B per lane (contiguous per-wave 1KB chunks)
__device__ __forceinline__ void gl_lds16(const void* g, void* l) {
    __builtin_amdgcn_global_load_lds((__attribute__((address_space(1))) u32*)g,
                                     (__attribute__((address_space(3))) u32*)l,
                                     16, 0, 0);
}

// Packed tile format: 128x64 tile = 16 chunks of 512 shorts; ch = c*8+ig;
// within chunk offset = lane*8+j holds [row=ig*16+(lane&15)][col=c*32+(lane>>4)*8+j].
// 64x64 tile = 8 chunks, ch = c*4+ig, same rule.

// ---------- pack kernel ----------

__global__ __launch_bounds__(256) void pack_tiles(
    const float* __restrict__ x,  short* __restrict__ xP,
    const float* __restrict__ y,  short* __restrict__ yP,
    const float* __restrict__ wqx, short* __restrict__ wqxP,
    const float* __restrict__ wqy, short* __restrict__ wqyP,
    const float* __restrict__ wpx, short* __restrict__ wpxP,
    const float* __restrict__ wpy, short* __restrict__ wpyP)
{
    const int tid  = threadIdx.x;
    const int w    = tid >> 6, lane = tid & 63;
    const int lam  = lane & 15, quad = lane >> 4;

    int t = blockIdx.x;
    const float* src; short* dst;
    if (t < 384)                 { src = x;   dst = xP; }
    else if ((t -= 384) < 384)   { src = y;   dst = yP; }
    else if ((t -= 384) < 216)   { src = wqx; dst = wqxP; }
    else if ((t -= 216) < 216)   { src = wqy; dst = wqyP; }
    else if ((t -= 216) < 72)    { src = wpx; dst = wpxP; }
    else                         { t -= 72;  src = wpy; dst = wpyP; }

    const int kb = t % 12, rb = t / 12;
    const int m0 = rb * 128, k0 = kb * 64;
    short* dtile = dst + (size_t)t * 8192;

    #pragma unroll
    for (int u = 0; u < 2; u++) {
        const int ig = w * 2 + u;
        #pragma unroll
        for (int c = 0; c < 2; c++) {
            const float* sp = src + (size_t)(m0 + ig * 16 + lam) * 768 + k0 + c * 32 + quad * 8;
            f32x4 a = *(const f32x4*)sp;
            f32x4 b = *(const f32x4*)(sp + 4);
            s16x8 o;
            o[0] = f2bf(a.x); o[1] = f2bf(a.y); o[2] = f2bf(a.z); o[3] = f2bf(a.w);
            o[4] = f2bf(b.x); o[5] = f2bf(b.y); o[6] = f2bf(b.z); o[7] = f2bf(b.w);
            *(s16x8*)(dtile + (c * 8 + ig) * 512 + lane * 8) = o;
        }
    }
}

// ---------- QKV GEMM (R5/R6 staged structure + Q pre-scale fold) ----------

__device__ __forceinline__ void stage_qkv(
    const short* __restrict__ At, const short* __restrict__ Wt,
    short* __restrict__ dA, short* __restrict__ dB, int w, int lane)
{
    #pragma unroll
    for (int c = 0; c < 2; c++)
        #pragma unroll
        for (int h = 0; h < 2; h++) {
            const int ch = c * 8 + w + h * 4;
            gl_lds16(At + ch * 512 + lane * 8, dA + ch * 512);
            gl_lds16(Wt + ch * 512 + lane * 8, dB + ch * 512);
        }
}

__global__ __launch_bounds__(256, 2) void qkv_gemm(
    const short* __restrict__ AxP, const short* __restrict__ AyP,
    const short* __restrict__ WxP, const short* __restrict__ WyP,
    const float* __restrict__ biasx, const float* __restrict__ biasy,
    const float* __restrict__ gqx, const float* __restrict__ bqx,
    const float* __restrict__ gkx, const float* __restrict__ bkx,
    const float* __restrict__ gqy, const float* __restrict__ bqy,
    const float* __restrict__ gky, const float* __restrict__ bky,
    short* __restrict__ Q, short* __restrict__ KP, short* __restrict__ VP)
{
    __shared__ union {
        struct { short a[8192]; short b[8192]; } st;     // staging (32 KB)
        short e[4][5120];                                 // epilogue transpose (40 KB)
    } uL;
    const int tid  = threadIdx.x;
    const int w    = tid >> 6, lane = tid & 63;
    const int lam  = lane & 15, quad = lane >> 4;
    const int strm = blockIdx.z;
    const int mblk = blockIdx.x;          // id%8 == mblk%8 -> XCD stripe
    const int nblk = blockIdx.y;
    const short* AP   = strm ? AyP : AxP;
    const short* WP   = strm ? WyP : WxP;
    const float* bias = strm ? biasy : biasx;
    const int m0 = mblk * 128;
    const int n0 = nblk * 128;
    const int wm = w >> 1, wn = w & 1;

    const f32x4 fzero = {0.f, 0.f, 0.f, 0.f};
    f32x4 acc[4][4];
    #pragma unroll
    for (int i = 0; i < 4; i++)
        #pragma unroll
        for (int t = 0; t < 4; t++) acc[i][t] = fzero;

    for (int kb = 0; kb < 12; ++kb) {
        __syncthreads();
        stage_qkv(AP + (size_t)(mblk * 12 + kb) * 8192,
                  WP + (size_t)(nblk * 12 + kb) * 8192,
                  uL.st.a, uL.st.b, w, lane);
        __syncthreads();
        s16x8 af[2][4], bfr[2][4];
        #pragma unroll
        for (int c = 0; c < 2; c++)
            #pragma unroll
            for (int i = 0; i < 4; i++)
                af[c][i] = *(const s16x8*)(uL.st.a + ((c * 8 + wm * 4 + i) * 64 + lane) * 8);
        #pragma unroll
        for (int c = 0; c < 2; c++)
            #pragma unroll
            for (int t = 0; t < 4; t++)
                bfr[c][t] = *(const s16x8*)(uL.st.b + ((c * 8 + wn * 4 + t) * 64 + lane) * 8);
        #pragma unroll
        for (int c = 0; c < 2; c++)
            #pragma unroll
            for (int i = 0; i < 4; i++)
                #pragma unroll
                for (int t = 0; t < 4; t++)
                    acc[i][t] = mfma32(af[c][i], bfr[c][t], acc[i][t]);
    }
    __syncthreads();                       // all reads done before union reuse

    // ---- epilogue ----
    const int nb     = n0 + wn * 64;
    const int region = nb / 768;               // 0=q, 1=k, 2=v
    const int head   = (nb % 768) / 64;
    const int mg0    = m0 + wm * 64;
    const int b_     = mg0 >> 10;
    const int sg0    = (mg0 & 1023) + strm * 1024;
    short* myE = uL.e[w];

    float bv[4];
    #pragma unroll
    for (int t = 0; t < 4; t++) bv[t] = bias[nb + t * 16 + lam];
    float gv[4], bb[4];
    if (region < 2) {
        const float* gp = (region == 0) ? (strm ? gqy : gqx) : (strm ? gky : gkx);
        const float* bp = (region == 0) ? (strm ? bqy : bqx) : (strm ? bky : bkx);
        const float qs  = (region == 0) ? 0.18033688011112042f : 1.0f;  // 0.125*log2(e)
        #pragma unroll
        for (int t = 0; t < 4; t++) { gv[t] = gp[t * 16 + lam] * qs; bb[t] = bp[t * 16 + lam] * qs; }
    }

    #pragma unroll
    for (int i = 0; i < 4; i++) {
        #pragma unroll
        for (int reg = 0; reg < 4; reg++) {
            const int lr = i * 16 + quad * 4 + reg;    // local row 0..63
            float v0 = acc[i][0][reg] + bv[0];
            float v1 = acc[i][1][reg] + bv[1];
            float v2 = acc[i][2][reg] + bv[2];
            float v3 = acc[i][3][reg] + bv[3];
            if (region < 2) {
                float s = v0 + v1 + v2 + v3;
                s += __shfl_xor(s, 1); s += __shfl_xor(s, 2);
                s += __shfl_xor(s, 4); s += __shfl_xor(s, 8);
                const float mean = s * (1.f / 64.f);
                const float c0 = v0 - mean, c1 = v1 - mean, c2 = v2 - mean, c3 = v3 - mean;
                float q2 = c0 * c0 + c1 * c1 + c2 * c2 + c3 * c3;
                q2 += __shfl_xor(q2, 1); q2 += __shfl_xor(q2, 2);
                q2 += __shfl_xor(q2, 4); q2 += __shfl_xor(q2, 8);
                const float rs = rsqrtf(q2 * (1.f / 64.f) + 1e-5f);
                v0 = c0 * rs * gv[0] + bb[0];
                v1 = c1 * rs * gv[1] + bb[1];
                v2 = c2 * rs * gv[2] + bb[2];
                v3 = c3 * rs * gv[3] + bb[3];
                myE[lr * 80 + 0 * 16 + lam] = f2bf(v0);   // row-major [s][d]
                myE[lr * 80 + 1 * 16 + lam] = f2bf(v1);
                myE[lr * 80 + 2 * 16 + lam] = f2bf(v2);
                myE[lr * 80 + 3 * 16 + lam] = f2bf(v3);
            } else {
                myE[(0 * 16 + lam) * 80 + lr] = f2bf(v0); // transposed [d][s]
                myE[(1 * 16 + lam) * 80 + lr] = f2bf(v1);
                myE[(2 * 16 + lam) * 80 + lr] = f2bf(v2);
                myE[(3 * 16 + lam) * 80 + lr] = f2bf(v3);
            }
        }
    }

    if (region == 0) {
        const int l8 = lane >> 3, c8 = (lane & 7) * 8;
        short* dstp = Q + ((size_t)(b_ * 12 + head) * 2048 + sg0) * 64;
        #pragma unroll
        for (int j = 0; j < 8; j++) {
            const int rr = j * 8 + l8;
            *(s16x8*)(dstp + (size_t)rr * 64 + c8) = *(const s16x8*)(myE + rr * 80 + c8);
        }
    } else {
        short* dstp = (region == 1 ? KP : VP) +
                      ((size_t)(b_ * 12 + head) * 32 + (sg0 >> 6)) * 4096;
        #pragma unroll
        for (int c = 0; c < 2; c++)
            #pragma unroll
            for (int ig = 0; ig < 4; ig++) {
                s16x8 vv = *(const s16x8*)(myE + (ig * 16 + lam) * 80 + c * 32 + quad * 8);
                *(s16x8*)(dstp + (c * 4 + ig) * 512 + lane * 8) = vv;
            }
    }
}

// ---------- flash attention v6: R6 shape + explicit K-frag register dbuf ----------
// 128q/block (32q/wave), direct contiguous loads. kf for iter N+1 issued during
// iter N (manual even/odd unroll -> no dynamic reg indexing); vf issued at iter
// start, consumed after softmax. Q pre-scaled; -30 in MFMA C-init.

__global__ __launch_bounds__(256, 3) void attn(
    const short* __restrict__ Q, const short* __restrict__ KP,
    const short* __restrict__ VP, short* __restrict__ OP)
{
    __shared__ __align__(16) short lP[4][2560];   // per-wave P roundtrip / O transpose
    const int tid  = threadIdx.x;
    const int w    = tid >> 6, lane = tid & 63;
    const int lam  = lane & 15, quad = lane >> 4;
    const int bh   = blockIdx.x;                  // all q-blocks of a bh on one XCD
    const int q0   = blockIdx.y * 128 + w * 32;
    const short* Qb  = Q  + (size_t)bh * 2048 * 64;
    const short* KPb = KP + (size_t)bh * 32 * 4096;
    const short* VPb = VP + (size_t)bh * 32 * 4096;
    short* myP = lP[w];

    s16x8 aq[2][2];
    #pragma unroll
    for (int qf = 0; qf < 2; qf++)
        #pragma unroll
        for (int c = 0; c < 2; c++)
            aq[qf][c] = *(const s16x8*)(Qb + (size_t)(q0 + qf * 16 + lam) * 64 + c * 32 + quad * 8);

    const f32x4 fzero = {0.f, 0.f, 0.f, 0.f};
    const f32x4 minit = {-30.f, -30.f, -30.f, -30.f};
    f32x4 o[2][4];
    float lsum[2][4];
    #pragma unroll
    for (int qf = 0; qf < 2; qf++) {
        #pragma unroll
        for (int t = 0; t < 4; t++) o[qf][t] = fzero;
        #pragma unroll
        for (int r = 0; r < 4; r++) lsum[qf][r] = 0.f;
    }

    s16x8 kfA[4][2], kfB[4][2];
    #pragma unroll
    for (int t = 0; t < 4; t++) {
        kfA[t][0] = *(const s16x8*)(KPb + (0 * 4 + t) * 512 + lane * 8);
        kfA[t][1] = *(const s16x8*)(KPb + (1 * 4 + t) * 512 + lane * 8);
    }

    #define ATTN_STEP(KCUR, KNXT, IT)                                                   \
        {                                                                               \
            const short* vt = VPb + (size_t)(IT) * 4096;                                \
            s16x8 vf[4][2];                                                             \
            _Pragma("unroll")                                                           \
            for (int t = 0; t < 4; t++) {                                               \
                vf[t][0] = *(const s16x8*)(vt + (0 * 4 + t) * 512 + lane * 8);          \
                vf[t][1] = *(const s16x8*)(vt + (1 * 4 + t) * 512 + lane * 8);          \
            }                                                                           \
            if ((IT) + 1 < 32) {                                                        \
                const short* ktn = KPb + (size_t)((IT) + 1) * 4096;                     \
                _Pragma("unroll")                                                       \
                for (int t = 0; t < 4; t++) {                                           \
                    KNXT[t][0] = *(const s16x8*)(ktn + (0 * 4 + t) * 512 + lane * 8);   \
                    KNXT[t][1] = *(const s16x8*)(ktn + (1 * 4 + t) * 512 + lane * 8);   \
                }                                                                       \
            }                                                                           \
            _Pragma("unroll")                                                           \
            for (int qf = 0; qf < 2; qf++) {                                            \
                f32x4 sc[4];                                                            \
                _Pragma("unroll")                                                       \
                for (int t = 0; t < 4; t++) sc[t] = minit;                              \
                _Pragma("unroll")                                                       \
                for (int t = 0; t < 4; t++) {                                           \
                    sc[t] = mfma32(aq[qf][0], KCUR[t][0], sc[t]);                       \
                    sc[t] = mfma32(aq[qf][1], KCUR[t][1], sc[t]);                       \
                }                                                                       \
                _Pragma("unroll")                                                       \
                for (int t = 0; t < 4; t++) {                                           \
                    const int g = t * 2 + (lam >> 3);                                   \
                    _Pragma("unroll")                                                   \
                    for (int r = 0; r < 4; r++) {                                       \
                        const float p = __builtin_amdgcn_exp2f(sc[t][r]);               \
                        lsum[qf][r] += p;                                               \
                        myP[(g * 17 + quad * 4 + r) * 8 + (lam & 7)] = f2bf(p);         \
                    }                                                                   \
                }                                                                       \
                s16x8 ap0 = *(const s16x8*)(myP + (quad * 17 + lam) * 8);               \
                s16x8 ap1 = *(const s16x8*)(myP + ((4 + quad) * 17 + lam) * 8);         \
                _Pragma("unroll")                                                       \
                for (int t = 0; t < 4; t++) {                                           \
                    o[qf][t] = mfma32(ap0, vf[t][0], o[qf][t]);                         \
                    o[qf][t] = mfma32(ap1, vf[t][1], o[qf][t]);                         \
                }                                                                       \
            }                                                                           \
        }

    for (int it2 = 0; it2 < 16; ++it2) {
        ATTN_STEP(kfA, kfB, it2 * 2);
        ATTN_STEP(kfB, kfA, it2 * 2 + 1);
    }
    #undef ATTN_STEP

    // ---- epilogue: normalize, per-wave transpose, packed O tiles ----
    short* myO = myP;
    #pragma unroll
    for (int qf = 0; qf < 2; qf++) {
        #pragma unroll
        for (int r = 0; r < 4; r++) {
            float l = lsum[qf][r];
            l += __shfl_xor(l, 1); l += __shfl_xor(l, 2);
            l += __shfl_xor(l, 4); l += __shfl_xor(l, 8);
            const float inv = 1.0f / l;
            const int row = qf * 16 + quad * 4 + r;       // 0..31 within wave
            #pragma unroll
            for (int t = 0; t < 4; t++)
                myO[row * 80 + t * 16 + lam] = f2bf(o[qf][t][r] * inv);
        }
    }

    const int b_ = bh / 12, h_ = bh % 12;
    const int strm = q0 >> 10;
    const int s    = q0 & 1023;
    const int sb   = s >> 6;
    short* dstp = OP + (((size_t)((strm * 4 + b_) * 16 + sb)) * 12 + h_) * 4096;
    const int igb = (s & 63) >> 4;
    #pragma unroll
    for (int u = 0; u < 2; u++) {
        const int ig = igb + u;
        #pragma unroll
        for (int c = 0; c < 2; c++) {
            s16x8 vv = *(const s16x8*)(myO + (u * 16 + lam) * 80 + c * 32 + quad * 8);
            *(s16x8*)(dstp + (c * 4 + ig) * 512 + lane * 8) = vv;
        }
    }
}

// ---------- proj GEMM (unchanged R5 structure) ----------

__device__ __forceinline__ void stage_proj(
    const short* __restrict__ Ot, const short* __restrict__ Wt,
    short* __restrict__ dA, short* __restrict__ dB, int w, int lane)
{
    #pragma unroll
    for (int u = 0; u < 2; u++) {
        const int ch = w * 2 + u;
        gl_lds16(Ot + ch * 512 + lane * 8, dA + ch * 512);
    }
    #pragma unroll
    for (int c = 0; c < 2; c++)
        #pragma unroll
        for (int h = 0; h < 2; h++) {
            const int ch = c * 8 + w + h * 4;
            gl_lds16(Wt + ch * 512 + lane * 8, dB + ch * 512);
        }
}

__global__ __launch_bounds__(256, 3) void proj_gemm(
    const short* __restrict__ OP,
    const short* __restrict__ WpxP, const short* __restrict__ WpyP,
    const float* __restrict__ bpx, const float* __restrict__ bpy,
    float* __restrict__ out)
{
    __shared__ __align__(16) short lA[2][4096];
    __shared__ __align__(16) short lB[2][8192];
    const int tid  = threadIdx.x;
    const int w    = tid >> 6, lane = tid & 63;
    const int lam  = lane & 15, quad = lane >> 4;
    const int strm = blockIdx.z;
    const short* WP   = strm ? WpyP : WpxP;
    const float* bias = strm ? bpy : bpx;
    const int m0 = blockIdx.x * 64;
    const int n0 = blockIdx.y * 128;
    const int wm = w >> 1, wn = w & 1;

    const int b_ = m0 >> 10, sb = (m0 & 1023) >> 6;
    const size_t tA0 = ((size_t)((strm * 4 + b_) * 16 + sb)) * 12;
    const size_t tB0 = (size_t)blockIdx.y * 12;

    const f32x4 fzero = {0.f, 0.f, 0.f, 0.f};
    f32x4 acc[2][4];
    #pragma unroll
    for (int i = 0; i < 2; i++)
        #pragma unroll
        for (int t = 0; t < 4; t++) acc[i][t] = fzero;

    stage_proj(OP + tA0 * 4096, WP + tB0 * 8192, lA[0], lB[0], w, lane);
    __syncthreads();

    int bi = 0;
    for (int kb = 0; kb < 12; ++kb) {
        if (kb + 1 < 12)
            stage_proj(OP + (tA0 + kb + 1) * 4096, WP + (tB0 + kb + 1) * 8192,
                       lA[bi ^ 1], lB[bi ^ 1], w, lane);

        const short* cA = lA[bi];
        const short* cB = lB[bi];
        s16x8 af[2][2], bfr[2][4];
        #pragma unroll
        for (int c = 0; c < 2; c++)
            #pragma unroll
            for (int i = 0; i < 2; i++)
                af[c][i] = *(const s16x8*)(cA + ((c * 4 + wm * 2 + i) * 64 + lane) * 8);
        #pragma unroll
        for (int c = 0; c < 2; c++)
            #pragma unroll
            for (int t = 0; t < 4; t++)
                bfr[c][t] = *(const s16x8*)(cB + ((c * 8 + wn * 4 + t) * 64 + lane) * 8);
        #pragma unroll
        for (int c = 0; c < 2; c++)
            #pragma unroll
            for (int i = 0; i < 2; i++)
                #pragma unroll
                for (int t = 0; t < 4; t++)
                    acc[i][t] = mfma32(af[c][i], bfr[c][t], acc[i][t]);

        __syncthreads();
        bi ^= 1;
    }

    const int nb = n0 + wn * 64;
    float bv[4];
    #pragma unroll
    for (int t = 0; t < 4; t++) bv[t] = bias[nb + t * 16 + lam];
    #pragma unroll
    for (int i = 0; i < 2; i++) {
        #pragma unroll
        for (int reg = 0; reg < 4; reg++) {
            const int mg = m0 + wm * 32 + i * 16 + quad * 4 + reg;
            float* dst = out + (size_t)strm * 3145728 + (size_t)mg * 768 + nb;
            #pragma unroll
            for (int t = 0; t < 4; t++) dst[t * 16 + lam] = acc[i][t][reg] + bv[t];
        }
    }
}

// ---------- launch ----------

#define WS_XP  0
#define WS_YP  6291456
#define WS_WQX 12582912
#define WS_WQY 16121856
#define WS_WPX 19660800
#define WS_WPY 20840448
#define WS_Q   22020096
#define WS_KP  34603008
#define WS_VP  47185920
#define WS_OP  59768832

extern "C" void kernel_launch(void* const* d_in, const int* in_sizes, int n_in,
                              void* d_out, int out_size, void* d_ws, size_t ws_size,
                              hipStream_t stream) {
    (void)in_sizes; (void)n_in; (void)out_size; (void)ws_size;
    const float* x       = (const float*)d_in[0];
    const float* y       = (const float*)d_in[1];
    const float* Wqkv_x  = (const float*)d_in[2];
    const float* bqkv_x  = (const float*)d_in[3];
    const float* Wqkv_y  = (const float*)d_in[4];
    const float* bqkv_y  = (const float*)d_in[5];
    const float* Wproj_x = (const float*)d_in[6];
    const float* bproj_x = (const float*)d_in[7];
    const float* Wproj_y = (const float*)d_in[8];
    const float* bproj_y = (const float*)d_in[9];
    const float* gq_x = (const float*)d_in[10];
    const float* bq_x = (const float*)d_in[11];
    const float* gk_x = (const float*)d_in[12];
    const float* bk_x = (const float*)d_in[13];
    const float* gq_y = (const float*)d_in[14];
    const float* bq_y = (const float*)d_in[15];
    const float* gk_y = (const float*)d_in[16];
    const float* bk_y = (const float*)d_in[17];

    char* ws = (char*)d_ws;
    short* xP   = (short*)(ws + WS_XP);
    short* yP   = (short*)(ws + WS_YP);
    short* wqxP = (short*)(ws + WS_WQX);
    short* wqyP = (short*)(ws + WS_WQY);
    short* wpxP = (short*)(ws + WS_WPX);
    short* wpyP = (short*)(ws + WS_WPY);
    short* Qb   = (short*)(ws + WS_Q);
    short* KPb  = (short*)(ws + WS_KP);
    short* VPb  = (short*)(ws + WS_VP);
    short* OPb  = (short*)(ws + WS_OP);

    pack_tiles<<<1344, 256, 0, stream>>>(x, xP, y, yP, Wqkv_x, wqxP,
                                         Wqkv_y, wqyP, Wproj_x, wpxP, Wproj_y, wpyP);

    dim3 g1(32, 18, 2);
    qkv_gemm<<<g1, 256, 0, stream>>>(xP, yP, wqxP, wqyP, bqkv_x, bqkv_y,
                                     gq_x, bq_x, gk_x, bk_x,
                                     gq_y, bq_y, gk_y, bk_y,
                                     Qb, KPb, VPb);

    dim3 g2(48, 16);
    attn<<<g2, 256, 0, stream>>>(Qb, KPb, VPb, OPb);

    dim3 g3(64, 6, 2);
    proj_gemm<<<g3, 256, 0, stream>>>(OPb, wpxP, wpyP, bproj_x, bproj_y, (float*)d_out);
}

// Round 11
// 246.794 us; speedup vs baseline: 1.2002x; 1.2002x over previous
//
#include <hip/hip_runtime.h>
#include <stdint.h>

typedef unsigned int u32;
typedef __attribute__((ext_vector_type(8))) __bf16 bf16x8;
typedef __attribute__((ext_vector_type(8))) short s16x8;
typedef __attribute__((ext_vector_type(4))) short s16x4;
typedef __attribute__((ext_vector_type(4))) float f32x4;

// ---------- helpers ----------

__device__ __forceinline__ short f2bf(float f) {
    __bf16 h = (__bf16)f;               // native v_cvt, RNE
    return __builtin_bit_cast(short, h);
}

__device__ __forceinline__ bf16x8 asbf(s16x8 v) {
    return __builtin_bit_cast(bf16x8, v);
}

__device__ __forceinline__ f32x4 mfma32(s16x8 a, s16x8 b, f32x4 c) {
    return __builtin_amdgcn_mfma_f32_16x16x32_bf16(asbf(a), asbf(b), c, 0, 0, 0);
}

// async global->LDS, 16B per lane (contiguous per-wave 1KB chunks)
__device__ __forceinline__ void gl_lds16(const void* g, void* l) {
    __builtin_amdgcn_global_load_lds((__attribute__((address_space(1))) u32*)g,
                                     (__attribute__((address_space(3))) u32*)l,
                                     16, 0, 0);
}

// Packed tile format: 128x64 tile = 16 chunks of 512 shorts; ch = c*8+ig;
// within chunk offset = lane*8+j holds [row=ig*16+(lane&15)][col=c*32+(lane>>4)*8+j].
// 64x64 tile = 8 chunks, ch = c*4+ig, same rule.

// ---------- pack kernel ----------

__global__ __launch_bounds__(256) void pack_tiles(
    const float* __restrict__ x,  short* __restrict__ xP,
    const float* __restrict__ y,  short* __restrict__ yP,
    const float* __restrict__ wqx, short* __restrict__ wqxP,
    const float* __restrict__ wqy, short* __restrict__ wqyP,
    const float* __restrict__ wpx, short* __restrict__ wpxP,
    const float* __restrict__ wpy, short* __restrict__ wpyP)
{
    const int tid  = threadIdx.x;
    const int w    = tid >> 6, lane = tid & 63;
    const int lam  = lane & 15, quad = lane >> 4;

    int t = blockIdx.x;
    const float* src; short* dst;
    if (t < 384)                 { src = x;   dst = xP; }
    else if ((t -= 384) < 384)   { src = y;   dst = yP; }
    else if ((t -= 384) < 216)   { src = wqx; dst = wqxP; }
    else if ((t -= 216) < 216)   { src = wqy; dst = wqyP; }
    else if ((t -= 216) < 72)    { src = wpx; dst = wpxP; }
    else                         { t -= 72;  src = wpy; dst = wpyP; }

    const int kb = t % 12, rb = t / 12;
    const int m0 = rb * 128, k0 = kb * 64;
    short* dtile = dst + (size_t)t * 8192;

    #pragma unroll
    for (int u = 0; u < 2; u++) {
        const int ig = w * 2 + u;
        #pragma unroll
        for (int c = 0; c < 2; c++) {
            const float* sp = src + (size_t)(m0 + ig * 16 + lam) * 768 + k0 + c * 32 + quad * 8;
            f32x4 a = *(const f32x4*)sp;
            f32x4 b = *(const f32x4*)(sp + 4);
            s16x8 o;
            o[0] = f2bf(a.x); o[1] = f2bf(a.y); o[2] = f2bf(a.z); o[3] = f2bf(a.w);
            o[4] = f2bf(b.x); o[5] = f2bf(b.y); o[6] = f2bf(b.z); o[7] = f2bf(b.w);
            *(s16x8*)(dtile + (c * 8 + ig) * 512 + lane * 8) = o;
        }
    }
}

// ---------- QKV GEMM (R5 staged structure + Q pre-scale fold) ----------

__device__ __forceinline__ void stage_qkv(
    const short* __restrict__ At, const short* __restrict__ Wt,
    short* __restrict__ dA, short* __restrict__ dB, int w, int lane)
{
    #pragma unroll
    for (int c = 0; c < 2; c++)
        #pragma unroll
        for (int h = 0; h < 2; h++) {
            const int ch = c * 8 + w + h * 4;
            gl_lds16(At + ch * 512 + lane * 8, dA + ch * 512);
            gl_lds16(Wt + ch * 512 + lane * 8, dB + ch * 512);
        }
}

__global__ __launch_bounds__(256, 2) void qkv_gemm(
    const short* __restrict__ AxP, const short* __restrict__ AyP,
    const short* __restrict__ WxP, const short* __restrict__ WyP,
    const float* __restrict__ biasx, const float* __restrict__ biasy,
    const float* __restrict__ gqx, const float* __restrict__ bqx,
    const float* __restrict__ gkx, const float* __restrict__ bkx,
    const float* __restrict__ gqy, const float* __restrict__ bqy,
    const float* __restrict__ gky, const float* __restrict__ bky,
    short* __restrict__ Q, short* __restrict__ KP, short* __restrict__ VP)
{
    __shared__ union {
        struct { short a[8192]; short b[8192]; } st;     // staging (32 KB)
        short e[4][5120];                                 // epilogue transpose (40 KB)
    } uL;
    const int tid  = threadIdx.x;
    const int w    = tid >> 6, lane = tid & 63;
    const int lam  = lane & 15, quad = lane >> 4;
    const int strm = blockIdx.z;
    const int mblk = blockIdx.x;          // id%8 == mblk%8 -> XCD stripe
    const int nblk = blockIdx.y;
    const short* AP   = strm ? AyP : AxP;
    const short* WP   = strm ? WyP : WxP;
    const float* bias = strm ? biasy : biasx;
    const int m0 = mblk * 128;
    const int n0 = nblk * 128;
    const int wm = w >> 1, wn = w & 1;

    const f32x4 fzero = {0.f, 0.f, 0.f, 0.f};
    f32x4 acc[4][4];
    #pragma unroll
    for (int i = 0; i < 4; i++)
        #pragma unroll
        for (int t = 0; t < 4; t++) acc[i][t] = fzero;

    for (int kb = 0; kb < 12; ++kb) {
        __syncthreads();
        stage_qkv(AP + (size_t)(mblk * 12 + kb) * 8192,
                  WP + (size_t)(nblk * 12 + kb) * 8192,
                  uL.st.a, uL.st.b, w, lane);
        __syncthreads();
        s16x8 af[2][4], bfr[2][4];
        #pragma unroll
        for (int c = 0; c < 2; c++)
            #pragma unroll
            for (int i = 0; i < 4; i++)
                af[c][i] = *(const s16x8*)(uL.st.a + ((c * 8 + wm * 4 + i) * 64 + lane) * 8);
        #pragma unroll
        for (int c = 0; c < 2; c++)
            #pragma unroll
            for (int t = 0; t < 4; t++)
                bfr[c][t] = *(const s16x8*)(uL.st.b + ((c * 8 + wn * 4 + t) * 64 + lane) * 8);
        #pragma unroll
        for (int c = 0; c < 2; c++)
            #pragma unroll
            for (int i = 0; i < 4; i++)
                #pragma unroll
                for (int t = 0; t < 4; t++)
                    acc[i][t] = mfma32(af[c][i], bfr[c][t], acc[i][t]);
    }
    __syncthreads();                       // all reads done before union reuse

    // ---- epilogue ----
    const int nb     = n0 + wn * 64;
    const int region = nb / 768;               // 0=q, 1=k, 2=v
    const int head   = (nb % 768) / 64;
    const int mg0    = m0 + wm * 64;
    const int b_     = mg0 >> 10;
    const int sg0    = (mg0 & 1023) + strm * 1024;
    short* myE = uL.e[w];

    float bv[4];
    #pragma unroll
    for (int t = 0; t < 4; t++) bv[t] = bias[nb + t * 16 + lam];
    float gv[4], bb[4];
    if (region < 2) {
        const float* gp = (region == 0) ? (strm ? gqy : gqx) : (strm ? gky : gkx);
        const float* bp = (region == 0) ? (strm ? bqy : bqx) : (strm ? bky : bkx);
        const float qs  = (region == 0) ? 0.18033688011112042f : 1.0f;  // 0.125*log2(e)
        #pragma unroll
        for (int t = 0; t < 4; t++) { gv[t] = gp[t * 16 + lam] * qs; bb[t] = bp[t * 16 + lam] * qs; }
    }

    #pragma unroll
    for (int i = 0; i < 4; i++) {
        #pragma unroll
        for (int reg = 0; reg < 4; reg++) {
            const int lr = i * 16 + quad * 4 + reg;    // local row 0..63
            float v0 = acc[i][0][reg] + bv[0];
            float v1 = acc[i][1][reg] + bv[1];
            float v2 = acc[i][2][reg] + bv[2];
            float v3 = acc[i][3][reg] + bv[3];
            if (region < 2) {
                float s = v0 + v1 + v2 + v3;
                s += __shfl_xor(s, 1); s += __shfl_xor(s, 2);
                s += __shfl_xor(s, 4); s += __shfl_xor(s, 8);
                const float mean = s * (1.f / 64.f);
                const float c0 = v0 - mean, c1 = v1 - mean, c2 = v2 - mean, c3 = v3 - mean;
                float q2 = c0 * c0 + c1 * c1 + c2 * c2 + c3 * c3;
                q2 += __shfl_xor(q2, 1); q2 += __shfl_xor(q2, 2);
                q2 += __shfl_xor(q2, 4); q2 += __shfl_xor(q2, 8);
                const float rs = rsqrtf(q2 * (1.f / 64.f) + 1e-5f);
                v0 = c0 * rs * gv[0] + bb[0];
                v1 = c1 * rs * gv[1] + bb[1];
                v2 = c2 * rs * gv[2] + bb[2];
                v3 = c3 * rs * gv[3] + bb[3];
                myE[lr * 80 + 0 * 16 + lam] = f2bf(v0);   // row-major [s][d]
                myE[lr * 80 + 1 * 16 + lam] = f2bf(v1);
                myE[lr * 80 + 2 * 16 + lam] = f2bf(v2);
                myE[lr * 80 + 3 * 16 + lam] = f2bf(v3);
            } else {
                myE[(0 * 16 + lam) * 80 + lr] = f2bf(v0); // transposed [d][s]
                myE[(1 * 16 + lam) * 80 + lr] = f2bf(v1);
                myE[(2 * 16 + lam) * 80 + lr] = f2bf(v2);
                myE[(3 * 16 + lam) * 80 + lr] = f2bf(v3);
            }
        }
    }

    if (region == 0) {
        const int l8 = lane >> 3, c8 = (lane & 7) * 8;
        short* dstp = Q + ((size_t)(b_ * 12 + head) * 2048 + sg0) * 64;
        #pragma unroll
        for (int j = 0; j < 8; j++) {
            const int rr = j * 8 + l8;
            *(s16x8*)(dstp + (size_t)rr * 64 + c8) = *(const s16x8*)(myE + rr * 80 + c8);
        }
    } else {
        short* dstp = (region == 1 ? KP : VP) +
                      ((size_t)(b_ * 12 + head) * 32 + (sg0 >> 6)) * 4096;
        #pragma unroll
        for (int c = 0; c < 2; c++)
            #pragma unroll
            for (int ig = 0; ig < 4; ig++) {
                s16x8 vv = *(const s16x8*)(myE + (ig * 16 + lam) * 80 + c * 32 + quad * 8);
                *(s16x8*)(dstp + (c * 4 + ig) * 512 + lane * 8) = vv;
            }
    }
}

// ---------- flash attention v7: R6-exact shape + VALU cuts ----------
// 128q/block (32q/wave), direct contiguous loads, per-wave P roundtrip.
// Q pre-scaled by 0.125*log2e; -30 in MFMA C-init -> bare v_exp_f32.
// All P-LDS addressing: one precomputed base + compile-time immediates.
// Walking kt/vt pointers. No register double-buffer (R10 spill lesson).

__global__ __launch_bounds__(256, 2) void attn(
    const short* __restrict__ Q, const short* __restrict__ KP,
    const short* __restrict__ VP, short* __restrict__ OP)
{
    __shared__ __align__(16) short lP[4][2560];   // per-wave P roundtrip / O transpose
    const int tid  = threadIdx.x;
    const int w    = tid >> 6, lane = tid & 63;
    const int lam  = lane & 15, quad = lane >> 4;
    const int bh   = blockIdx.x;                  // all q-blocks of a bh on one XCD
    const int q0   = blockIdx.y * 128 + w * 32;
    const short* Qb = Q  + (size_t)bh * 2048 * 64;
    const short* kt = KP + (size_t)bh * 32 * 4096;
    const short* vt = VP + (size_t)bh * 32 * 4096;
    short* myP = lP[w];
    // P write base: expansion of ((t*2+(lam>>3))*17 + quad*4 + r)*8 + (lam&7)
    short* pw = myP + (lam >> 3) * 136 + quad * 32 + (lam & 7);
    const short* pr0 = myP + (quad * 17 + lam) * 8;
    const short* pr1 = myP + ((4 + quad) * 17 + lam) * 8;

    s16x8 aq[2][2];
    #pragma unroll
    for (int qf = 0; qf < 2; qf++)
        #pragma unroll
        for (int c = 0; c < 2; c++)
            aq[qf][c] = *(const s16x8*)(Qb + (size_t)(q0 + qf * 16 + lam) * 64 + c * 32 + quad * 8);

    const f32x4 fzero = {0.f, 0.f, 0.f, 0.f};
    const f32x4 minit = {-30.f, -30.f, -30.f, -30.f};
    f32x4 o[2][4];
    float lsum[2][4];
    #pragma unroll
    for (int qf = 0; qf < 2; qf++) {
        #pragma unroll
        for (int t = 0; t < 4; t++) o[qf][t] = fzero;
        #pragma unroll
        for (int r = 0; r < 4; r++) lsum[qf][r] = 0.f;
    }

    for (int it = 0; it < 32; ++it) {
        s16x8 kf[4][2], vf[4][2];
        #pragma unroll
        for (int t = 0; t < 4; t++) {
            kf[t][0] = *(const s16x8*)(kt + (0 * 4 + t) * 512 + lane * 8);
            kf[t][1] = *(const s16x8*)(kt + (1 * 4 + t) * 512 + lane * 8);
            vf[t][0] = *(const s16x8*)(vt + (0 * 4 + t) * 512 + lane * 8);
            vf[t][1] = *(const s16x8*)(vt + (1 * 4 + t) * 512 + lane * 8);
        }

        #pragma unroll
        for (int qf = 0; qf < 2; qf++) {
            f32x4 sc[4];
            #pragma unroll
            for (int t = 0; t < 4; t++) sc[t] = minit;
            #pragma unroll
            for (int t = 0; t < 4; t++) {
                sc[t] = mfma32(aq[qf][0], kf[t][0], sc[t]);
                sc[t] = mfma32(aq[qf][1], kf[t][1], sc[t]);
            }
            #pragma unroll
            for (int t = 0; t < 4; t++)
                #pragma unroll
                for (int r = 0; r < 4; r++) {
                    const float p = __builtin_amdgcn_exp2f(sc[t][r]);
                    lsum[qf][r] += p;
                    pw[t * 272 + r * 8] = f2bf(p);   // base + const imm
                }
            s16x8 ap0 = *(const s16x8*)pr0;
            s16x8 ap1 = *(const s16x8*)pr1;
            #pragma unroll
            for (int t = 0; t < 4; t++) {
                o[qf][t] = mfma32(ap0, vf[t][0], o[qf][t]);
                o[qf][t] = mfma32(ap1, vf[t][1], o[qf][t]);
            }
        }
        kt += 4096;
        vt += 4096;
    }

    // ---- epilogue: normalize, per-wave transpose, packed O tiles ----
    short* myO = myP;
    #pragma unroll
    for (int qf = 0; qf < 2; qf++) {
        #pragma unroll
        for (int r = 0; r < 4; r++) {
            float l = lsum[qf][r];
            l += __shfl_xor(l, 1); l += __shfl_xor(l, 2);
            l += __shfl_xor(l, 4); l += __shfl_xor(l, 8);
            const float inv = 1.0f / l;
            const int row = qf * 16 + quad * 4 + r;       // 0..31 within wave
            #pragma unroll
            for (int t = 0; t < 4; t++)
                myO[row * 80 + t * 16 + lam] = f2bf(o[qf][t][r] * inv);
        }
    }

    const int b_ = bh / 12, h_ = bh % 12;
    const int strm = q0 >> 10;
    const int s    = q0 & 1023;
    const int sb   = s >> 6;
    short* dstp = OP + (((size_t)((strm * 4 + b_) * 16 + sb)) * 12 + h_) * 4096;
    const int igb = (s & 63) >> 4;
    #pragma unroll
    for (int u = 0; u < 2; u++) {
        const int ig = igb + u;
        #pragma unroll
        for (int c = 0; c < 2; c++) {
            s16x8 vv = *(const s16x8*)(myO + (u * 16 + lam) * 80 + c * 32 + quad * 8);
            *(s16x8*)(dstp + (c * 4 + ig) * 512 + lane * 8) = vv;
        }
    }
}

// ---------- proj GEMM (unchanged R5 structure) ----------

__device__ __forceinline__ void stage_proj(
    const short* __restrict__ Ot, const short* __restrict__ Wt,
    short* __restrict__ dA, short* __restrict__ dB, int w, int lane)
{
    #pragma unroll
    for (int u = 0; u < 2; u++) {
        const int ch = w * 2 + u;
        gl_lds16(Ot + ch * 512 + lane * 8, dA + ch * 512);
    }
    #pragma unroll
    for (int c = 0; c < 2; c++)
        #pragma unroll
        for (int h = 0; h < 2; h++) {
            const int ch = c * 8 + w + h * 4;
            gl_lds16(Wt + ch * 512 + lane * 8, dB + ch * 512);
        }
}

__global__ __launch_bounds__(256, 3) void proj_gemm(
    const short* __restrict__ OP,
    const short* __restrict__ WpxP, const short* __restrict__ WpyP,
    const float* __restrict__ bpx, const float* __restrict__ bpy,
    float* __restrict__ out)
{
    __shared__ __align__(16) short lA[2][4096];
    __shared__ __align__(16) short lB[2][8192];
    const int tid  = threadIdx.x;
    const int w    = tid >> 6, lane = tid & 63;
    const int lam  = lane & 15, quad = lane >> 4;
    const int strm = blockIdx.z;
    const short* WP   = strm ? WpyP : WpxP;
    const float* bias = strm ? bpy : bpx;
    const int m0 = blockIdx.x * 64;
    const int n0 = blockIdx.y * 128;
    const int wm = w >> 1, wn = w & 1;

    const int b_ = m0 >> 10, sb = (m0 & 1023) >> 6;
    const size_t tA0 = ((size_t)((strm * 4 + b_) * 16 + sb)) * 12;
    const size_t tB0 = (size_t)blockIdx.y * 12;

    const f32x4 fzero = {0.f, 0.f, 0.f, 0.f};
    f32x4 acc[2][4];
    #pragma unroll
    for (int i = 0; i < 2; i++)
        #pragma unroll
        for (int t = 0; t < 4; t++) acc[i][t] = fzero;

    stage_proj(OP + tA0 * 4096, WP + tB0 * 8192, lA[0], lB[0], w, lane);
    __syncthreads();

    int bi = 0;
    for (int kb = 0; kb < 12; ++kb) {
        if (kb + 1 < 12)
            stage_proj(OP + (tA0 + kb + 1) * 4096, WP + (tB0 + kb + 1) * 8192,
                       lA[bi ^ 1], lB[bi ^ 1], w, lane);

        const short* cA = lA[bi];
        const short* cB = lB[bi];
        s16x8 af[2][2], bfr[2][4];
        #pragma unroll
        for (int c = 0; c < 2; c++)
            #pragma unroll
            for (int i = 0; i < 2; i++)
                af[c][i] = *(const s16x8*)(cA + ((c * 4 + wm * 2 + i) * 64 + lane) * 8);
        #pragma unroll
        for (int c = 0; c < 2; c++)
            #pragma unroll
            for (int t = 0; t < 4; t++)
                bfr[c][t] = *(const s16x8*)(cB + ((c * 8 + wn * 4 + t) * 64 + lane) * 8);
        #pragma unroll
        for (int c = 0; c < 2; c++)
            #pragma unroll
            for (int i = 0; i < 2; i++)
                #pragma unroll
                for (int t = 0; t < 4; t++)
                    acc[i][t] = mfma32(af[c][i], bfr[c][t], acc[i][t]);

        __syncthreads();
        bi ^= 1;
    }

    const int nb = n0 + wn * 64;
    float bv[4];
    #pragma unroll
    for (int t = 0; t < 4; t++) bv[t] = bias[nb + t * 16 + lam];
    #pragma unroll
    for (int i = 0; i < 2; i++) {
        #pragma unroll
        for (int reg = 0; reg < 4; reg++) {
            const int mg = m0 + wm * 32 + i * 16 + quad * 4 + reg;
            float* dst = out + (size_t)strm * 3145728 + (size_t)mg * 768 + nb;
            #pragma unroll
            for (int t = 0; t < 4; t++) dst[t * 16 + lam] = acc[i][t][reg] + bv[t];
        }
    }
}

// ---------- launch ----------

#define WS_XP  0
#define WS_YP  6291456
#define WS_WQX 12582912
#define WS_WQY 16121856
#define WS_WPX 19660800
#define WS_WPY 20840448
#define WS_Q   22020096
#define WS_KP  34603008
#define WS_VP  47185920
#define WS_OP  59768832

extern "C" void kernel_launch(void* const* d_in, const int* in_sizes, int n_in,
                              void* d_out, int out_size, void* d_ws, size_t ws_size,
                              hipStream_t stream) {
    (void)in_sizes; (void)n_in; (void)out_size; (void)ws_size;
    const float* x       = (const float*)d_in[0];
    const float* y       = (const float*)d_in[1];
    const float* Wqkv_x  = (const float*)d_in[2];
    const float* bqkv_x  = (const float*)d_in[3];
    const float* Wqkv_y  = (const float*)d_in[4];
    const float* bqkv_y  = (const float*)d_in[5];
    const float* Wproj_x = (const float*)d_in[6];
    const float* bproj_x = (const float*)d_in[7];
    const float* Wproj_y = (const float*)d_in[8];
    const float* bproj_y = (const float*)d_in[9];
    const float* gq_x = (const float*)d_in[10];
    const float* bq_x = (const float*)d_in[11];
    const float* gk_x = (const float*)d_in[12];
    const float* bk_x = (const float*)d_in[13];
    const float* gq_y = (const float*)d_in[14];
    const float* bq_y = (const float*)d_in[15];
    const float* gk_y = (const float*)d_in[16];
    const float* bk_y = (const float*)d_in[17];

    char* ws = (char*)d_ws;
    short* xP   = (short*)(ws + WS_XP);
    short* yP   = (short*)(ws + WS_YP);
    short* wqxP = (short*)(ws + WS_WQX);
    short* wqyP = (short*)(ws + WS_WQY);
    short* wpxP = (short*)(ws + WS_WPX);
    short* wpyP = (short*)(ws + WS_WPY);
    short* Qb   = (short*)(ws + WS_Q);
    short* KPb  = (short*)(ws + WS_KP);
    short* VPb  = (short*)(ws + WS_VP);
    short* OPb  = (short*)(ws + WS_OP);

    pack_tiles<<<1344, 256, 0, stream>>>(x, xP, y, yP, Wqkv_x, wqxP,
                                         Wqkv_y, wqyP, Wproj_x, wpxP, Wproj_y, wpyP);

    dim3 g1(32, 18, 2);
    qkv_gemm<<<g1, 256, 0, stream>>>(xP, yP, wqxP, wqyP, bqkv_x, bqkv_y,
                                     gq_x, bq_x, gk_x, bk_x,
                                     gq_y, bq_y, gk_y, bk_y,
                                     Qb, KPb, VPb);

    dim3 g2(48, 16);
    attn<<<g2, 256, 0, stream>>>(Qb, KPb, VPb, OPb);

    dim3 g3(64, 6, 2);
    proj_gemm<<<g3, 256, 0, stream>>>(OPb, wpxP, wpyP, bproj_x, bproj_y, (float*)d_out);
}